// Round 14
// baseline (420.186 us; speedup 1.0000x reference)
//
#include <hip/hip_runtime.h>
#include <cstdint>
#include <cmath>

#define NBATCH   8
#define NPB      500000
#define PRE_NMS  6000
#define POST_NMS 1000
#define NWORDS   94          // ceil(6000/64)
#define NBINS    16384       // 14-bit float prefix (sign+exp+5 mantissa)
#define HBLK     16          // histogram partial blocks per batch
#define CANDCAP  8192        // candidate cap per batch (expected ~6800 worst case)
#define BBOX_CLIP 4.135166556742356f   // log(1000/16)
#define TI 16                // mask rows per block (4 per wave) — 24 regressed (r11)
#define TJ 512               // mask j-tile staged in LDS
#define WIN 16               // scan window (64 % WIN == 0: word boundary every 4 windows)
#define CNT_PAD 64           // counter stride in uints (256 B): one cache line per batch
#define SORT_CHUNK 2048      // bitonic phases k<=2048 are chunk-local -> parallel blocks

#define F_SORT 1u
#define F_COMP 2u
#define F_OOB  4u

// monotone map: ascending uint <=> ascending float
__device__ __forceinline__ unsigned monot(float f) {
    unsigned b = __float_as_uint(f);
    return (b & 0x80000000u) ? ~b : (b | 0x80000000u);
}

// EXACT replacement for (__fdiv_rn(inter,den) > 0.7f), den > 0 (see round 8):
__device__ __forceinline__ bool iou_gt_thr(float inter, float den) {
    const double MID = (double)0.7f + 0x1p-25;
    return (double)inter >= MID * (double)den;
}

// ------ Phase 1a: per-block partial histograms (plain stores, no memset) ----
__global__ __launch_bounds__(256) void hist_kernel(const float* __restrict__ obj,
                                                   unsigned* __restrict__ hist) {
    __shared__ unsigned lh[NBINS];   // 64 KiB
    const int b = blockIdx.y, blk = blockIdx.x;
    for (int q = threadIdx.x; q < NBINS; q += 256) lh[q] = 0;
    __syncthreads();
    const float* p = obj + (size_t)b * NPB;
    const int stride = HBLK * 256;
    for (int i = blk * 256 + threadIdx.x; i < NPB; i += stride) {
        unsigned u = monot(p[i]);
        atomicAdd(&lh[u >> 18], 1u);
    }
    __syncthreads();
    unsigned* gh = hist + ((size_t)b * HBLK + blk) * NBINS;
    for (int q = threadIdx.x; q < NBINS; q += 256) gh[q] = lh[q];  // full write: no pre-zero
}

// --- Phase 1b: sum partials in-register, find threshold bin, zero counters ---
__global__ __launch_bounds__(256) void thresh_kernel(const unsigned* __restrict__ hist,
                                                     unsigned* __restrict__ tbin,
                                                     unsigned* __restrict__ ccnt,
                                                     unsigned* __restrict__ flags,
                                                     unsigned long long* __restrict__ cand) {
    __shared__ unsigned part[256], pre[256];
    const int b = blockIdx.x, t = threadIdx.x;
    const unsigned* hb = hist + (size_t)b * HBLK * NBINS;
    const int PER = NBINS / 256;     // 64 bins per thread, contiguous descending
    unsigned bv[PER];
    unsigned s = 0;
#pragma unroll
    for (int d = 0; d < PER; ++d) {
        const int bin = NBINS - 1 - (t * PER + d);
        unsigned v = 0;
#pragma unroll
        for (int k = 0; k < HBLK; ++k) v += hb[(size_t)k * NBINS + bin];
        bv[d] = v;
        s += v;
    }
    part[t] = s;
    __syncthreads();
    if (t == 0) {
        unsigned run = 0;
        for (int q = 0; q < 256; ++q) { pre[q] = run; run += part[q]; }
    }
    __syncthreads();
    unsigned c = pre[t];
    if (c < PRE_NMS && c + part[t] >= PRE_NMS) {
        unsigned run = c;
#pragma unroll
        for (int d = 0; d < PER; ++d) {
            run += bv[d];
            if (run >= PRE_NMS) { tbin[b] = (unsigned)(NBINS - 1 - (t * PER + d)); break; }
        }
    }
    // zero-init per-batch counters/flags/candidate sentinels (replaces ws memset)
    if (t == 0) { ccnt[(size_t)b * CNT_PAD] = 0; flags[b] = 0; }
    unsigned long long* cb = cand + (size_t)b * CANDCAP;
    for (int q = t; q < CANDCAP; q += 256) cb[q] = 0ULL;   // 0 = -inf sentinel
}

// ------ Phase 1c: compact candidates — WAVE-AGGREGATED atomics --------------
__global__ __launch_bounds__(256) void compact_kernel(const float* __restrict__ obj,
                                                      const unsigned* __restrict__ tbin,
                                                      unsigned long long* __restrict__ cand,
                                                      unsigned* __restrict__ ccnt) {
    const int b = blockIdx.y;
    const unsigned T = tbin[b];
    const float* p = obj + (size_t)b * NPB;
    unsigned long long* cb = cand + (size_t)b * CANDCAP;
    const int lane = threadIdx.x & 63;
    const int stride = gridDim.x * 256;
    for (int i = blockIdx.x * 256 + threadIdx.x; i < NPB; i += stride) {
        unsigned u = monot(p[i]);
        const bool pred = (u >> 18) >= T;
        unsigned long long bal = __ballot(pred);
        if (bal == 0) continue;                      // common case: skip
        unsigned base = 0;
        // lane 0 has the smallest i in the wave -> active whenever any lane is
        if (lane == 0) base = atomicAdd(&ccnt[(size_t)b * CNT_PAD], __popcll(bal));
        base = (unsigned)__shfl((int)base, 0);
        if (pred) {
            unsigned pos = base + (unsigned)__popcll(bal & ((1ULL << lane) - 1ULL));
            if (pos < CANDCAP)  // composite: value desc, then index asc (via ~i)
                cb[pos] = ((unsigned long long)u << 32) | (unsigned)(~i);
        }
    }
}

// ---- Phase 1d-i: bitonic phases k=2..2048 — chunk-local, 32 parallel blocks -
__global__ __launch_bounds__(512) void sort_local_kernel(unsigned long long* __restrict__ cand) {
    __shared__ unsigned long long s[SORT_CHUNK];  // 16 KiB
    const int blk = blockIdx.x;
    const int b = blk >> 2, c = blk & 3;          // 4 chunks per batch
    unsigned long long* cb = cand + (size_t)b * CANDCAP + (size_t)c * SORT_CHUNK;
    const int t = threadIdx.x;
    for (int i = t; i < SORT_CHUNK; i += 512) s[i] = cb[i];
    __syncthreads();
    for (unsigned k = 2; k <= SORT_CHUNK; k <<= 1) {
        const bool kfull = (k == SORT_CHUNK);
        const bool upfull = (c & 1) == 0;         // global bit 11 == chunk parity
        for (unsigned j = k >> 1; j > 0; j >>= 1) {
            for (unsigned ii = t; ii < SORT_CHUNK; ii += 512) {
                unsigned l = ii ^ j;
                if (l > ii) {
                    unsigned long long a = s[ii], d = s[l];
                    bool up = kfull ? upfull : ((ii & k) == 0);
                    if (up ? (a < d) : (a > d)) { s[ii] = d; s[l] = a; }
                }
            }
            __syncthreads();
        }
    }
    for (int i = t; i < SORT_CHUNK; i += 512) cb[i] = s[i];
}

// ---- Phase 1d-ii: bitonic merge k=4096,8192 (25 passes) + checks + emit ----
__global__ __launch_bounds__(1024) void sort_merge_kernel(const unsigned long long* __restrict__ cand,
                                                          const float* __restrict__ obj,
                                                          unsigned* __restrict__ topk,
                                                          unsigned* __restrict__ flags) {
    __shared__ unsigned long long s[CANDCAP];  // 64 KiB
    const int b = blockIdx.x, t = threadIdx.x;
    const unsigned long long* cb = cand + (size_t)b * CANDCAP;
    for (int i = t; i < CANDCAP; i += 1024) s[i] = cb[i];
    __syncthreads();
    for (unsigned k = 2 * SORT_CHUNK; k <= CANDCAP; k <<= 1) {
        for (unsigned j = k >> 1; j > 0; j >>= 1) {
            for (unsigned ii = t; ii < CANDCAP; ii += 1024) {
                unsigned l = ii ^ j;
                if (l > ii) {
                    unsigned long long a = s[ii], c = s[l];
                    bool up = (ii & k) == 0;
                    if (up ? (a < c) : (a > c)) { s[ii] = c; s[l] = a; }
                }
            }
            __syncthreads();
        }
    }
    // ---- checks + emit ----
    unsigned f = 0;
    for (int r = t; r < PRE_NMS; r += 1024) {
        unsigned long long c = s[r];
        unsigned idx = ~(unsigned)(c & 0xffffffffULL);
        if (idx >= NPB) { f |= F_OOB; idx = 0; }
        else if (monot(obj[(size_t)b * NPB + idx]) != (unsigned)(c >> 32)) f |= F_COMP;
        if (r < PRE_NMS - 1 && !(c > s[r + 1])) f |= F_SORT;
        topk[(size_t)b * PRE_NMS + r] = idx;
    }
    if (f) atomicOr(&flags[b], f);
}

// ---------------- Phase 2: decode + clip + valid (numerics FROZEN) ----------
__global__ __launch_bounds__(256) void decode_kernel(const float* __restrict__ anchors,
                                                     const float* __restrict__ deltas,
                                                     const unsigned* __restrict__ topk,
                                                     const int* __restrict__ imh,
                                                     const int* __restrict__ imw,
                                                     float* __restrict__ boxes,
                                                     float* __restrict__ areas,
                                                     unsigned long long* __restrict__ validm) {
    const int b = blockIdx.y;
    const int r = blockIdx.x * 256 + threadIdx.x;
    const bool active = r < PRE_NMS;
    int vh = imh[0], vw = imw[0];
    float ih = (vh > 0 && vh < (1 << 20)) ? (float)vh : __int_as_float(vh);
    float iw = (vw > 0 && vw < (1 << 20)) ? (float)vw : __int_as_float(vw);
    bool valid = false;
    if (active) {
        unsigned idx = topk[(size_t)b * PRE_NMS + r];
        if (idx >= NPB) idx = 0;   // canary will have fired; avoid OOB
        const float4 a = ((const float4*)anchors)[(size_t)b * NPB + idx];
        const float4 d = ((const float4*)deltas)[(size_t)b * NPB + idx];
        float wa = a.z - a.x, ha = a.w - a.y;
        float cxa = a.x + 0.5f * wa, cya = a.y + 0.5f * ha;  // 0.5*x exact: fma-safe
        float dw = fminf(d.z, BBOX_CLIP), dh = fminf(d.w, BBOX_CLIP);
        float cx = __fadd_rn(__fmul_rn(d.x, wa), cxa);
        float cy = __fadd_rn(__fmul_rn(d.y, ha), cya);
        float ew = (float)::exp((double)dw), eh = (float)::exp((double)dh);
        float w = __fmul_rn(ew, wa), h = __fmul_rn(eh, ha);
        float x1 = cx - 0.5f * w, y1 = cy - 0.5f * h;
        float x2 = cx + 0.5f * w, y2 = cy + 0.5f * h;
        x1 = fminf(fmaxf(x1, 0.f), iw); y1 = fminf(fmaxf(y1, 0.f), ih);
        x2 = fminf(fmaxf(x2, 0.f), iw); y2 = fminf(fmaxf(y2, 0.f), ih);
        valid = (x2 - x1 >= 1.0f) && (y2 - y1 >= 1.0f);
        ((float4*)boxes)[(size_t)b * PRE_NMS + r] = make_float4(x1, y1, x2, y2);
        areas[(size_t)b * PRE_NMS + r] = __fmul_rn(x2 - x1, y2 - y1);
    }
    unsigned long long bal = __ballot(valid);
    int w = r >> 6;
    if ((threadIdx.x & 63) == 0 && w < NWORDS) validm[(size_t)b * NWORDS + w] = bal;
}

// ------- Phase 3: suppression bitmask — 4 rows/wave (round-10 config) -------
__global__ __launch_bounds__(256) void mask_kernel(const float* __restrict__ boxes,
                                                   const float* __restrict__ areas,
                                                   unsigned long long* __restrict__ mask,
                                                   unsigned long long* __restrict__ diag) {
    __shared__ float4 sb[TJ];
    __shared__ float  sa[TJ];
    const int b = blockIdx.x & 7;            // XCD pin: block -> XCD round-robin
    const int i0 = (blockIdx.x >> 3) * TI;
    const int jbase = (i0 >> 6) << 6;
    const int wv = threadIdx.x >> 6, ln = threadIdx.x & 63;
    const int ir = i0 + 4 * wv;              // 4 rows per wave; 6000 % 16 == 0
    unsigned long long* dgp = diag + (size_t)b * PRE_NMS;
    float4 bx[4]; float ar[4]; int wlo[4];
    unsigned long long* rowp[4];
#pragma unroll
    for (int r = 0; r < 4; ++r) {
        const int i = ir + r;
        bx[r]   = ((const float4*)boxes)[(size_t)b * PRE_NMS + i];
        ar[r]   = areas[(size_t)b * PRE_NMS + i];
        rowp[r] = mask + ((size_t)b * PRE_NMS + i) * NWORDS;
        wlo[r]  = i >> 6;
    }
    for (int t0 = jbase; t0 < NWORDS * 64; t0 += TJ) {
        for (int e = threadIdx.x; e < TJ; e += 256) {
            int j = t0 + e;
            if (j < PRE_NMS) {
                sb[e] = ((const float4*)boxes)[(size_t)b * PRE_NMS + j];
                sa[e] = areas[(size_t)b * PRE_NMS + j];
            } else { sb[e] = make_float4(0.f, 0.f, 0.f, 0.f); sa[e] = 0.f; }
        }
        __syncthreads();
        for (int wl = 0; wl < TJ / 64; ++wl) {
            const int w = (t0 >> 6) + wl;
            if (w >= NWORDS) break;
            const int e = wl * 64 + ln;
            const float4 bj = sb[e];
            const float aj = sa[e];
#pragma unroll
            for (int r = 0; r < 4; ++r) {
                // EXACT same f32 sequence as the passing kernels.
                float xx1 = fmaxf(bx[r].x, bj.x), yy1 = fmaxf(bx[r].y, bj.y);
                float xx2 = fminf(bx[r].z, bj.z), yy2 = fminf(bx[r].w, bj.w);
                float inter = __fmul_rn(fmaxf(__fsub_rn(xx2, xx1), 0.f),
                                        fmaxf(__fsub_rn(yy2, yy1), 0.f));
                float den = __fadd_rn(__fsub_rn(__fadd_rn(ar[r], aj), inter), 1e-9f);
                bool p = iou_gt_thr(inter, den);
                unsigned long long m = __ballot(p);
                if (ln == 0) {
                    if (w == wlo[r]) {
                        m &= ~((2ULL << ((ir + r) & 63)) - 1ULL);  // keep bits j>i only
                        rowp[r][w] = m;
                        dgp[ir + r] = m;
                    } else if (w > wlo[r]) {
                        rowp[r][w] = m;
                    }
                }
            }
        }
        __syncthreads();
    }
}

// ------- Phase 4: windowed scan v5 — depth-3 speculative, full-VGPR ---------
// __launch_bounds__(64,1): allow up to 512 VGPRs so all three speculative
// buffers stay register-resident (r13 compiled to 152 VGPR -> loads sunk).
__global__ __launch_bounds__(64, 1) void scan_kernel(const unsigned long long* __restrict__ mask,
                                                     const unsigned long long* __restrict__ diag,
                                                     const unsigned long long* __restrict__ validm,
                                                     const float* __restrict__ boxes,
                                                     const unsigned* __restrict__ flags,
                                                     const unsigned* __restrict__ ccnt,
                                                     float* __restrict__ out) {
    const int b = blockIdx.x, lane = threadIdx.x;
    const unsigned long long* mb = mask + (size_t)b * PRE_NMS * NWORDS;
    const unsigned long long* dg = diag + (size_t)b * PRE_NMS;
    const int w0 = 2 * lane, w1 = 2 * lane + 1;
    unsigned long long r_lo = (w0 < NWORDS) ? ~validm[(size_t)b * NWORDS + w0] : ~0ULL;
    unsigned long long r_hi = (w1 < NWORDS) ? ~validm[(size_t)b * NWORDS + w1] : ~0ULL;
    int count = 0;
    unsigned long long cw = 0;   // carried candidate bits of the current word

    uint4 MA[WIN], MB[WIN], MC[WIN];
    unsigned long long WA[WIN], WB[WIN], WC[WIN];
    float4 bxA, bxB, bxC;

#define ISSUE(M, W, BX, base_)                                                   \
    {                                                                            \
        const int bb_ = (base_);                                                 \
        const char* rb_ = (const char*)(mb + (size_t)bb_ * NWORDS);              \
        const unsigned long long* dgp_ = dg + bb_;   /* uniform -> s_load */     \
        _Pragma("unroll")                                                        \
        for (int q = 0; q < WIN; ++q) {                                          \
            M[q] = *(const uint4*)(rb_ + (size_t)q * (NWORDS * 8)                \
                                       + (size_t)lane * 16);                     \
            W[q] = dgp_[q];                                                      \
        }                                                                        \
        BX = (lane < WIN)                                                        \
                 ? ((const float4*)boxes)[(size_t)b * PRE_NMS + bb_ + lane]      \
                 : make_float4(0.f, 0.f, 0.f, 0.f);                              \
    }

#define RESOLVE(M, W, BX, base_)                                                 \
    {                                                                            \
        const int bb_ = (base_);                                                 \
        const int wR_ = bb_ >> 6, s0_ = bb_ & 63;                                \
        if (s0_ == 0) {    /* word boundary: one broadcast per word */           \
            const unsigned long long sel_ = (wR_ & 1) ? r_hi : r_lo;             \
            const int srcl_ = wR_ >> 1;                                          \
            const unsigned lo_ = (unsigned)__shfl((int)(unsigned)(sel_ & 0xffffffffULL), srcl_); \
            const unsigned hi_ = (unsigned)__shfl((int)(unsigned)(sel_ >> 32), srcl_);           \
            cw = ~(((unsigned long long)hi_ << 32) | lo_);                       \
        }                                                                        \
        unsigned cand_ = (unsigned)(cw >> s0_) & 0xFFFFu;                        \
        if (cand_) {                                                             \
            unsigned kept_ = 0;                                                  \
            const int cb_ = count;                                               \
            _Pragma("unroll")                                                    \
            for (int q = 0; q < WIN; ++q) {                                      \
                if (((cand_ >> q) & 1u) && count < POST_NMS) {                   \
                    kept_ |= 1u << q; ++count;                                   \
                    cw &= ~W[q];                                                 \
                    cand_ &= (unsigned)(cw >> s0_);                              \
                }                                                                \
            }                                                                    \
            const bool v0_ = (w0 >= wR_), v1_ = (w1 >= wR_);                     \
            _Pragma("unroll")                                                    \
            for (int q = 0; q < WIN; ++q) {                                      \
                if (kept_ & (1u << q)) {                                         \
                    const uint4 m_ = M[q];                                       \
                    if (v0_) r_lo |= ((unsigned long long)m_.y << 32) | m_.x;    \
                    if (v1_) r_hi |= ((unsigned long long)m_.w << 32) | m_.z;    \
                }                                                                \
            }                                                                    \
            if (lane < WIN && (kept_ & (1u << lane))) {                          \
                const int rank_ = cb_ + __popc(kept_ & ((1u << lane) - 1u));     \
                ((float4*)out)[(size_t)b * POST_NMS + rank_] = BX;               \
            }                                                                    \
        }                                                                        \
    }

    ISSUE(MA, WA, bxA, 0)
    ISSUE(MB, WB, bxB, WIN)
    bool done = false;
    for (int base = 0; base < PRE_NMS && !done; base += 3 * WIN) {
        const int n2 = base + 2 * WIN;
        ISSUE(MC, WC, bxC, (n2 < PRE_NMS) ? n2 : 0)
        RESOLVE(MA, WA, bxA, base)
        done = (count >= POST_NMS);
        if (!done) {
            const int n3 = base + 3 * WIN;
            ISSUE(MA, WA, bxA, (n3 < PRE_NMS) ? n3 : 0)
            RESOLVE(MB, WB, bxB, base + WIN)
            done = (count >= POST_NMS);
        }
        if (!done) {
            const int n4 = base + 4 * WIN;
            ISSUE(MB, WB, bxB, (n4 < PRE_NMS) ? n4 : 0)
            RESOLVE(MC, WC, bxC, base + 2 * WIN)
            done = (count >= POST_NMS);
        }
    }
#undef ISSUE
#undef RESOLVE

    // zero-fill unwritten ranks (replaces the out-buffer memset node)
    for (int r = count + (int)lane; r < POST_NMS; r += 64)
        ((float4*)out)[(size_t)b * POST_NMS + r] = make_float4(0.f, 0.f, 0.f, 0.f);

    // merged finalize: canary on invariant violation (absmax names the stage)
    if (lane == 0) {
        float canary = 0.f;
        const unsigned cc = ccnt[(size_t)b * CNT_PAD];
        const unsigned fl = flags[b];
        if (cc > CANDCAP)       canary = 111000.f;
        else if (cc < PRE_NMS)  canary = 222000.f;
        if (fl & F_SORT)        canary = 333000.f;
        if (fl & F_COMP)        canary = 444000.f;
        if (fl & F_OOB)         canary = 777000.f;
        if (canary != 0.f) out[(size_t)b * POST_NMS * 4] = canary;
    }
}

extern "C" void kernel_launch(void* const* d_in, const int* in_sizes, int n_in,
                              void* d_out, int out_size, void* d_ws, size_t ws_size,
                              hipStream_t stream) {
    const float* anchors = (const float*)d_in[0];
    const float* obj     = (const float*)d_in[1];
    const float* deltas  = (const float*)d_in[2];
    const int*   imh     = (const int*)d_in[3];
    const int*   imw     = (const int*)d_in[4];
    float* out = (float*)d_out;
    char* ws = (char*)d_ws;

    size_t off = 0;
    auto alloc = [&](size_t bytes) {
        size_t o = off;
        off = (off + bytes + 511) & ~(size_t)511;
        return o;
    };
    const size_t HPART = alloc((size_t)NBATCH * HBLK * NBINS * 4);   // 8 MB partials
    const size_t TBIN  = alloc((size_t)NBATCH * 4);
    const size_t CCNT  = alloc((size_t)NBATCH * CNT_PAD * 4);
    const size_t FLAGS = alloc((size_t)NBATCH * 4);
    const size_t CAND  = alloc((size_t)NBATCH * CANDCAP * 8);
    const size_t TOPK  = alloc((size_t)NBATCH * PRE_NMS * 4);
    const size_t BOX   = alloc((size_t)NBATCH * PRE_NMS * 16);
    const size_t AREA  = alloc((size_t)NBATCH * PRE_NMS * 4);
    const size_t VALID = alloc((size_t)NBATCH * NWORDS * 8);
    const size_t DIAG  = alloc((size_t)NBATCH * PRE_NMS * 8);
    const size_t MASK  = alloc((size_t)NBATCH * PRE_NMS * NWORDS * 8);
    (void)alloc(1024);   // pad: scan's dwordx4 row reads overrun rows by <=272B
    if (ws_size < off) return;  // visible failure: output left as harness zeros

    unsigned*            hist   = (unsigned*)(ws + HPART);
    unsigned*            tbin   = (unsigned*)(ws + TBIN);
    unsigned*            ccnt   = (unsigned*)(ws + CCNT);
    unsigned*            flags  = (unsigned*)(ws + FLAGS);
    unsigned long long*  cand   = (unsigned long long*)(ws + CAND);
    unsigned*            topk   = (unsigned*)(ws + TOPK);
    float*               boxes  = (float*)(ws + BOX);
    float*               areas  = (float*)(ws + AREA);
    unsigned long long*  validm = (unsigned long long*)(ws + VALID);
    unsigned long long*  diag   = (unsigned long long*)(ws + DIAG);
    unsigned long long*  maskp  = (unsigned long long*)(ws + MASK);

    // 8 graph nodes, no memsets: hist writes partials fully; thresh zeroes
    // ccnt/flags/cand; scan zero-fills the output tail itself.
    hist_kernel      <<<dim3(HBLK, NBATCH), 256, 0, stream>>>(obj, hist);
    thresh_kernel    <<<dim3(NBATCH), 256, 0, stream>>>(hist, tbin, ccnt, flags, cand);
    compact_kernel   <<<dim3(128, NBATCH), 256, 0, stream>>>(obj, tbin, cand, ccnt);
    sort_local_kernel<<<dim3(NBATCH * (CANDCAP / SORT_CHUNK)), 512, 0, stream>>>(cand);
    sort_merge_kernel<<<dim3(NBATCH), 1024, 0, stream>>>(cand, obj, topk, flags);
    decode_kernel    <<<dim3((PRE_NMS + 255) / 256, NBATCH), 256, 0, stream>>>(
        anchors, deltas, topk, imh, imw, boxes, areas, validm);
    mask_kernel      <<<dim3((PRE_NMS / TI) * NBATCH), 256, 0, stream>>>(
        boxes, areas, maskp, diag);
    scan_kernel      <<<dim3(NBATCH), 64, 0, stream>>>(
        maskp, diag, validm, boxes, flags, ccnt, out);
    (void)in_sizes; (void)n_in; (void)ws_size;
}

// Round 15
// 371.858 us; speedup vs baseline: 1.1300x; 1.1300x over previous
//
#include <hip/hip_runtime.h>
#include <cstdint>
#include <cmath>

#define NBATCH   8
#define NPB      500000
#define PRE_NMS  6000
#define POST_NMS 1000
#define NWORDS   94          // ceil(6000/64)
#define NBINS    16384       // 14-bit float prefix (sign+exp+5 mantissa)
#define CANDCAP  8192        // candidate cap per batch (expected ~6800 worst case)
#define BBOX_CLIP 4.135166556742356f   // log(1000/16)
#define TI 16                // mask rows per block (4 per wave) — 24 regressed (r11)
#define TJ 512               // mask j-tile staged in LDS
#define WIN 16               // scan window (64 % WIN == 0: word boundary every 4 windows)
#define CNT_PAD 64           // counter stride in uints (256 B): one cache line per batch
#define SORT_CHUNK 2048      // bitonic phases k<=2048 are chunk-local -> parallel blocks

#define F_SORT 1u
#define F_COMP 2u
#define F_OOB  4u

// monotone map: ascending uint <=> ascending float
__device__ __forceinline__ unsigned monot(float f) {
    unsigned b = __float_as_uint(f);
    return (b & 0x80000000u) ? ~b : (b | 0x80000000u);
}

// EXACT replacement for (__fdiv_rn(inter,den) > 0.7f), den > 0 (see round 8):
__device__ __forceinline__ bool iou_gt_thr(float inter, float den) {
    const double MID = (double)0.7f + 0x1p-25;
    return (double)inter >= MID * (double)den;
}

// ---------------- Phase 1a: 16384-bin histogram of key prefix ----------------
__global__ __launch_bounds__(256) void hist_kernel(const float* __restrict__ obj,
                                                   unsigned* __restrict__ hist) {
    __shared__ unsigned lh[NBINS];   // 64 KiB
    const int b = blockIdx.y;
    for (int q = threadIdx.x; q < NBINS; q += 256) lh[q] = 0;
    __syncthreads();
    const float* p = obj + (size_t)b * NPB;
    const int stride = gridDim.x * 256;
    for (int i = blockIdx.x * 256 + threadIdx.x; i < NPB; i += stride) {
        unsigned u = monot(p[i]);
        atomicAdd(&lh[u >> 18], 1u);
    }
    __syncthreads();
    unsigned* gh = hist + (size_t)b * NBINS;
    for (int q = threadIdx.x; q < NBINS; q += 256) {
        unsigned v = lh[q];
        if (v) atomicAdd(&gh[q], v);
    }
}

// ------- Phase 1b: find threshold bin (descending cumulative >= 6000) -------
__global__ __launch_bounds__(256) void thresh_kernel(const unsigned* __restrict__ hist,
                                                     unsigned* __restrict__ tbin) {
    __shared__ unsigned part[256], pre[256];
    const int b = blockIdx.x;
    const unsigned* gh = hist + (size_t)b * NBINS;
    const int t = threadIdx.x;
    const int PER = NBINS / 256;     // 64 bins per thread
    unsigned s = 0;
    for (int d = 0; d < PER; ++d) s += gh[NBINS - 1 - (t * PER + d)];
    part[t] = s;
    __syncthreads();
    if (t == 0) {
        unsigned run = 0;
        for (int q = 0; q < 256; ++q) { pre[q] = run; run += part[q]; }
    }
    __syncthreads();
    unsigned c = pre[t];
    if (c < PRE_NMS && c + part[t] >= PRE_NMS) {
        unsigned run = c;
        for (int d = 0; d < PER; ++d) {
            int bin = NBINS - 1 - (t * PER + d);
            run += gh[bin];
            if (run >= PRE_NMS) { tbin[b] = (unsigned)bin; break; }
        }
    }
}

// ------ Phase 1c: compact candidates — WAVE-AGGREGATED atomics --------------
__global__ __launch_bounds__(256) void compact_kernel(const float* __restrict__ obj,
                                                      const unsigned* __restrict__ tbin,
                                                      unsigned long long* __restrict__ cand,
                                                      unsigned* __restrict__ ccnt) {
    const int b = blockIdx.y;
    const unsigned T = tbin[b];
    const float* p = obj + (size_t)b * NPB;
    unsigned long long* cb = cand + (size_t)b * CANDCAP;
    const int lane = threadIdx.x & 63;
    const int stride = gridDim.x * 256;
    for (int i = blockIdx.x * 256 + threadIdx.x; i < NPB; i += stride) {
        unsigned u = monot(p[i]);
        const bool pred = (u >> 18) >= T;
        unsigned long long bal = __ballot(pred);
        if (bal == 0) continue;                      // common case: skip
        unsigned base = 0;
        // lane 0 has the smallest i in the wave -> active whenever any lane is
        if (lane == 0) base = atomicAdd(&ccnt[(size_t)b * CNT_PAD], __popcll(bal));
        base = (unsigned)__shfl((int)base, 0);
        if (pred) {
            unsigned pos = base + (unsigned)__popcll(bal & ((1ULL << lane) - 1ULL));
            if (pos < CANDCAP)  // composite: value desc, then index asc (via ~i)
                cb[pos] = ((unsigned long long)u << 32) | (unsigned)(~i);
        }
    }
}

// ---- Phase 1d-i: bitonic phases k=2..2048 — chunk-local, 32 parallel blocks -
__global__ __launch_bounds__(512) void sort_local_kernel(unsigned long long* __restrict__ cand) {
    __shared__ unsigned long long s[SORT_CHUNK];  // 16 KiB
    const int blk = blockIdx.x;
    const int b = blk >> 2, c = blk & 3;          // 4 chunks per batch
    unsigned long long* cb = cand + (size_t)b * CANDCAP + (size_t)c * SORT_CHUNK;
    const int t = threadIdx.x;
    for (int i = t; i < SORT_CHUNK; i += 512) s[i] = cb[i];
    __syncthreads();
    for (unsigned k = 2; k <= SORT_CHUNK; k <<= 1) {
        const bool kfull = (k == SORT_CHUNK);
        const bool upfull = (c & 1) == 0;         // global bit 11 == chunk parity
        for (unsigned j = k >> 1; j > 0; j >>= 1) {
            for (unsigned ii = t; ii < SORT_CHUNK; ii += 512) {
                unsigned l = ii ^ j;
                if (l > ii) {
                    unsigned long long a = s[ii], d = s[l];
                    bool up = kfull ? upfull : ((ii & k) == 0);
                    if (up ? (a < d) : (a > d)) { s[ii] = d; s[l] = a; }
                }
            }
            __syncthreads();
        }
    }
    for (int i = t; i < SORT_CHUNK; i += 512) cb[i] = s[i];
}

// ---- Phase 1d-ii: bitonic merge k=4096,8192 (25 passes) + checks + emit ----
__global__ __launch_bounds__(1024) void sort_merge_kernel(const unsigned long long* __restrict__ cand,
                                                          const float* __restrict__ obj,
                                                          unsigned* __restrict__ topk,
                                                          unsigned* __restrict__ flags) {
    __shared__ unsigned long long s[CANDCAP];  // 64 KiB
    const int b = blockIdx.x, t = threadIdx.x;
    const unsigned long long* cb = cand + (size_t)b * CANDCAP;
    for (int i = t; i < CANDCAP; i += 1024) s[i] = cb[i];
    __syncthreads();
    for (unsigned k = 2 * SORT_CHUNK; k <= CANDCAP; k <<= 1) {
        for (unsigned j = k >> 1; j > 0; j >>= 1) {
            for (unsigned ii = t; ii < CANDCAP; ii += 1024) {
                unsigned l = ii ^ j;
                if (l > ii) {
                    unsigned long long a = s[ii], c = s[l];
                    bool up = (ii & k) == 0;
                    if (up ? (a < c) : (a > c)) { s[ii] = c; s[l] = a; }
                }
            }
            __syncthreads();
        }
    }
    // ---- checks + emit ----
    unsigned f = 0;
    for (int r = t; r < PRE_NMS; r += 1024) {
        unsigned long long c = s[r];
        unsigned idx = ~(unsigned)(c & 0xffffffffULL);
        if (idx >= NPB) { f |= F_OOB; idx = 0; }
        else if (monot(obj[(size_t)b * NPB + idx]) != (unsigned)(c >> 32)) f |= F_COMP;
        if (r < PRE_NMS - 1 && !(c > s[r + 1])) f |= F_SORT;
        topk[(size_t)b * PRE_NMS + r] = idx;
    }
    if (f) atomicOr(&flags[b], f);
}

// ---------------- Phase 2: decode + clip + valid (numerics FROZEN) ----------
__global__ __launch_bounds__(256) void decode_kernel(const float* __restrict__ anchors,
                                                     const float* __restrict__ deltas,
                                                     const unsigned* __restrict__ topk,
                                                     const int* __restrict__ imh,
                                                     const int* __restrict__ imw,
                                                     float* __restrict__ boxes,
                                                     float* __restrict__ areas,
                                                     unsigned long long* __restrict__ validm) {
    const int b = blockIdx.y;
    const int r = blockIdx.x * 256 + threadIdx.x;
    const bool active = r < PRE_NMS;
    int vh = imh[0], vw = imw[0];
    float ih = (vh > 0 && vh < (1 << 20)) ? (float)vh : __int_as_float(vh);
    float iw = (vw > 0 && vw < (1 << 20)) ? (float)vw : __int_as_float(vw);
    bool valid = false;
    if (active) {
        unsigned idx = topk[(size_t)b * PRE_NMS + r];
        if (idx >= NPB) idx = 0;   // canary will have fired; avoid OOB
        const float4 a = ((const float4*)anchors)[(size_t)b * NPB + idx];
        const float4 d = ((const float4*)deltas)[(size_t)b * NPB + idx];
        float wa = a.z - a.x, ha = a.w - a.y;
        float cxa = a.x + 0.5f * wa, cya = a.y + 0.5f * ha;  // 0.5*x exact: fma-safe
        float dw = fminf(d.z, BBOX_CLIP), dh = fminf(d.w, BBOX_CLIP);
        float cx = __fadd_rn(__fmul_rn(d.x, wa), cxa);
        float cy = __fadd_rn(__fmul_rn(d.y, ha), cya);
        float ew = (float)::exp((double)dw), eh = (float)::exp((double)dh);
        float w = __fmul_rn(ew, wa), h = __fmul_rn(eh, ha);
        float x1 = cx - 0.5f * w, y1 = cy - 0.5f * h;
        float x2 = cx + 0.5f * w, y2 = cy + 0.5f * h;
        x1 = fminf(fmaxf(x1, 0.f), iw); y1 = fminf(fmaxf(y1, 0.f), ih);
        x2 = fminf(fmaxf(x2, 0.f), iw); y2 = fminf(fmaxf(y2, 0.f), ih);
        valid = (x2 - x1 >= 1.0f) && (y2 - y1 >= 1.0f);
        ((float4*)boxes)[(size_t)b * PRE_NMS + r] = make_float4(x1, y1, x2, y2);
        areas[(size_t)b * PRE_NMS + r] = __fmul_rn(x2 - x1, y2 - y1);
    }
    unsigned long long bal = __ballot(valid);
    int w = r >> 6;
    if ((threadIdx.x & 63) == 0 && w < NWORDS) validm[(size_t)b * NWORDS + w] = bal;
}

// ------- Phase 3: suppression bitmask — 4 rows/wave (round-10 config) -------
// j>i word-granular post-masking; j>=PRE_NMS via zero-padded boxes (exact-0).
// Emits diag[i] = row i's masked diagonal word for the scan's word-carry.
__global__ __launch_bounds__(256) void mask_kernel(const float* __restrict__ boxes,
                                                   const float* __restrict__ areas,
                                                   unsigned long long* __restrict__ mask,
                                                   unsigned long long* __restrict__ diag) {
    __shared__ float4 sb[TJ];
    __shared__ float  sa[TJ];
    const int b = blockIdx.x & 7;            // XCD pin: block -> XCD round-robin
    const int i0 = (blockIdx.x >> 3) * TI;
    const int jbase = (i0 >> 6) << 6;
    const int wv = threadIdx.x >> 6, ln = threadIdx.x & 63;
    const int ir = i0 + 4 * wv;              // 4 rows per wave; 6000 % 16 == 0
    unsigned long long* dgp = diag + (size_t)b * PRE_NMS;
    float4 bx[4]; float ar[4]; int wlo[4];
    unsigned long long* rowp[4];
#pragma unroll
    for (int r = 0; r < 4; ++r) {
        const int i = ir + r;
        bx[r]   = ((const float4*)boxes)[(size_t)b * PRE_NMS + i];
        ar[r]   = areas[(size_t)b * PRE_NMS + i];
        rowp[r] = mask + ((size_t)b * PRE_NMS + i) * NWORDS;
        wlo[r]  = i >> 6;
    }
    for (int t0 = jbase; t0 < NWORDS * 64; t0 += TJ) {
        for (int e = threadIdx.x; e < TJ; e += 256) {
            int j = t0 + e;
            if (j < PRE_NMS) {
                sb[e] = ((const float4*)boxes)[(size_t)b * PRE_NMS + j];
                sa[e] = areas[(size_t)b * PRE_NMS + j];
            } else { sb[e] = make_float4(0.f, 0.f, 0.f, 0.f); sa[e] = 0.f; }
        }
        __syncthreads();
        for (int wl = 0; wl < TJ / 64; ++wl) {
            const int w = (t0 >> 6) + wl;
            if (w >= NWORDS) break;
            const int e = wl * 64 + ln;
            const float4 bj = sb[e];
            const float aj = sa[e];
#pragma unroll
            for (int r = 0; r < 4; ++r) {
                // EXACT same f32 sequence as the passing kernels.
                float xx1 = fmaxf(bx[r].x, bj.x), yy1 = fmaxf(bx[r].y, bj.y);
                float xx2 = fminf(bx[r].z, bj.z), yy2 = fminf(bx[r].w, bj.w);
                float inter = __fmul_rn(fmaxf(__fsub_rn(xx2, xx1), 0.f),
                                        fmaxf(__fsub_rn(yy2, yy1), 0.f));
                float den = __fadd_rn(__fsub_rn(__fadd_rn(ar[r], aj), inter), 1e-9f);
                bool p = iou_gt_thr(inter, den);
                unsigned long long m = __ballot(p);
                if (ln == 0) {
                    if (w == wlo[r]) {
                        m &= ~((2ULL << ((ir + r) & 63)) - 1ULL);  // keep bits j>i only
                        rowp[r][w] = m;
                        dgp[ir + r] = m;
                    } else if (w > wlo[r]) {
                        rowp[r][w] = m;
                    }
                }
            }
        }
        __syncthreads();
    }
}

// ------- Phase 4: windowed scan v5 — depth-3 speculative, word-carry --------
__global__ __launch_bounds__(64) void scan_kernel(const unsigned long long* __restrict__ mask,
                                                  const unsigned long long* __restrict__ diag,
                                                  const unsigned long long* __restrict__ validm,
                                                  const float* __restrict__ boxes,
                                                  const unsigned* __restrict__ flags,
                                                  const unsigned* __restrict__ ccnt,
                                                  float* __restrict__ out) {
    const int b = blockIdx.x, lane = threadIdx.x;
    const unsigned long long* mb = mask + (size_t)b * PRE_NMS * NWORDS;
    const unsigned long long* dg = diag + (size_t)b * PRE_NMS;
    const int w0 = 2 * lane, w1 = 2 * lane + 1;
    unsigned long long r_lo = (w0 < NWORDS) ? ~validm[(size_t)b * NWORDS + w0] : ~0ULL;
    unsigned long long r_hi = (w1 < NWORDS) ? ~validm[(size_t)b * NWORDS + w1] : ~0ULL;
    int count = 0;
    unsigned long long cw = 0;   // carried candidate bits of the current word

    uint4 MA[WIN], MB[WIN], MC[WIN];
    unsigned long long WA[WIN], WB[WIN], WC[WIN];
    float4 bxA, bxB, bxC;

#define ISSUE(M, W, BX, base_)                                                   \
    {                                                                            \
        const int bb_ = (base_);                                                 \
        const char* rb_ = (const char*)(mb + (size_t)bb_ * NWORDS);              \
        const unsigned long long* dgp_ = dg + bb_;   /* uniform -> s_load */     \
        _Pragma("unroll")                                                        \
        for (int q = 0; q < WIN; ++q) {                                          \
            M[q] = *(const uint4*)(rb_ + (size_t)q * (NWORDS * 8)                \
                                       + (size_t)lane * 16);                     \
            W[q] = dgp_[q];                                                      \
        }                                                                        \
        BX = (lane < WIN)                                                        \
                 ? ((const float4*)boxes)[(size_t)b * PRE_NMS + bb_ + lane]      \
                 : make_float4(0.f, 0.f, 0.f, 0.f);                              \
    }

#define RESOLVE(M, W, BX, base_)                                                 \
    {                                                                            \
        const int bb_ = (base_);                                                 \
        const int wR_ = bb_ >> 6, s0_ = bb_ & 63;                                \
        if (s0_ == 0) {    /* word boundary: one broadcast per word */           \
            const unsigned long long sel_ = (wR_ & 1) ? r_hi : r_lo;             \
            const int srcl_ = wR_ >> 1;                                          \
            const unsigned lo_ = (unsigned)__shfl((int)(unsigned)(sel_ & 0xffffffffULL), srcl_); \
            const unsigned hi_ = (unsigned)__shfl((int)(unsigned)(sel_ >> 32), srcl_);           \
            cw = ~(((unsigned long long)hi_ << 32) | lo_);                       \
        }                                                                        \
        unsigned cand_ = (unsigned)(cw >> s0_) & 0xFFFFu;                        \
        if (cand_) {                                                             \
            unsigned kept_ = 0;                                                  \
            const int cb_ = count;                                               \
            _Pragma("unroll")                                                    \
            for (int q = 0; q < WIN; ++q) {                                      \
                if (((cand_ >> q) & 1u) && count < POST_NMS) {                   \
                    kept_ |= 1u << q; ++count;                                   \
                    cw &= ~W[q];                                                 \
                    cand_ &= (unsigned)(cw >> s0_);                              \
                }                                                                \
            }                                                                    \
            const bool v0_ = (w0 >= wR_), v1_ = (w1 >= wR_);                     \
            _Pragma("unroll")                                                    \
            for (int q = 0; q < WIN; ++q) {                                      \
                if (kept_ & (1u << q)) {                                         \
                    const uint4 m_ = M[q];                                       \
                    if (v0_) r_lo |= ((unsigned long long)m_.y << 32) | m_.x;    \
                    if (v1_) r_hi |= ((unsigned long long)m_.w << 32) | m_.z;    \
                }                                                                \
            }                                                                    \
            if (lane < WIN && (kept_ & (1u << lane))) {                          \
                const int rank_ = cb_ + __popc(kept_ & ((1u << lane) - 1u));     \
                ((float4*)out)[(size_t)b * POST_NMS + rank_] = BX;               \
            }                                                                    \
        }                                                                        \
    }

    ISSUE(MA, WA, bxA, 0)
    ISSUE(MB, WB, bxB, WIN)
    bool done = false;
    for (int base = 0; base < PRE_NMS && !done; base += 3 * WIN) {
        const int n2 = base + 2 * WIN;
        ISSUE(MC, WC, bxC, (n2 < PRE_NMS) ? n2 : 0)
        RESOLVE(MA, WA, bxA, base)
        done = (count >= POST_NMS);
        if (!done) {
            const int n3 = base + 3 * WIN;
            ISSUE(MA, WA, bxA, (n3 < PRE_NMS) ? n3 : 0)
            RESOLVE(MB, WB, bxB, base + WIN)
            done = (count >= POST_NMS);
        }
        if (!done) {
            const int n4 = base + 4 * WIN;
            ISSUE(MB, WB, bxB, (n4 < PRE_NMS) ? n4 : 0)
            RESOLVE(MC, WC, bxC, base + 2 * WIN)
            done = (count >= POST_NMS);
        }
    }
#undef ISSUE
#undef RESOLVE

    // merged finalize: canary on invariant violation (absmax names the stage)
    if (lane == 0) {
        float canary = 0.f;
        const unsigned cc = ccnt[(size_t)b * CNT_PAD];
        const unsigned fl = flags[b];
        if (cc > CANDCAP)       canary = 111000.f;
        else if (cc < PRE_NMS)  canary = 222000.f;
        if (fl & F_SORT)        canary = 333000.f;
        if (fl & F_COMP)        canary = 444000.f;
        if (fl & F_OOB)         canary = 777000.f;
        if (canary != 0.f) out[(size_t)b * POST_NMS * 4] = canary;
    }
}

extern "C" void kernel_launch(void* const* d_in, const int* in_sizes, int n_in,
                              void* d_out, int out_size, void* d_ws, size_t ws_size,
                              hipStream_t stream) {
    const float* anchors = (const float*)d_in[0];
    const float* obj     = (const float*)d_in[1];
    const float* deltas  = (const float*)d_in[2];
    const int*   imh     = (const int*)d_in[3];
    const int*   imw     = (const int*)d_in[4];
    float* out = (float*)d_out;
    char* ws = (char*)d_ws;

    size_t off = 0;
    auto alloc = [&](size_t bytes) {
        size_t o = off;
        off = (off + bytes + 511) & ~(size_t)511;
        return o;
    };
    // regions needing zero-init FIRST and contiguous -> single memset
    const size_t HIST  = alloc((size_t)NBATCH * NBINS * 4);
    const size_t TBIN  = alloc((size_t)NBATCH * 4);
    const size_t CCNT  = alloc((size_t)NBATCH * CNT_PAD * 4);
    const size_t FLAGS = alloc((size_t)NBATCH * 4);
    const size_t CAND  = alloc((size_t)NBATCH * CANDCAP * 8);
    const size_t ZEND  = off;
    const size_t TOPK  = alloc((size_t)NBATCH * PRE_NMS * 4);
    const size_t BOX   = alloc((size_t)NBATCH * PRE_NMS * 16);
    const size_t AREA  = alloc((size_t)NBATCH * PRE_NMS * 4);
    const size_t VALID = alloc((size_t)NBATCH * NWORDS * 8);
    const size_t DIAG  = alloc((size_t)NBATCH * PRE_NMS * 8);
    const size_t MASK  = alloc((size_t)NBATCH * PRE_NMS * NWORDS * 8);
    (void)alloc(1024);   // pad: scan's dwordx4 row reads overrun rows by <=272B
    if (ws_size < off) return;

    unsigned*            hist   = (unsigned*)(ws + HIST);
    unsigned*            tbin   = (unsigned*)(ws + TBIN);
    unsigned*            ccnt   = (unsigned*)(ws + CCNT);
    unsigned*            flags  = (unsigned*)(ws + FLAGS);
    unsigned long long*  cand   = (unsigned long long*)(ws + CAND);
    unsigned*            topk   = (unsigned*)(ws + TOPK);
    float*               boxes  = (float*)(ws + BOX);
    float*               areas  = (float*)(ws + AREA);
    unsigned long long*  validm = (unsigned long long*)(ws + VALID);
    unsigned long long*  diag   = (unsigned long long*)(ws + DIAG);
    unsigned long long*  maskp  = (unsigned long long*)(ws + MASK);

    hipMemsetAsync(ws, 0, ZEND, stream);   // hist+tbin+ccnt+flags+cand in one node
    hipMemsetAsync(out, 0, (size_t)out_size * sizeof(float), stream);

    hist_kernel      <<<dim3(32, NBATCH), 256, 0, stream>>>(obj, hist);   // 32: 1 block/CU (16 regressed, r10)
    thresh_kernel    <<<dim3(NBATCH), 256, 0, stream>>>(hist, tbin);
    compact_kernel   <<<dim3(128, NBATCH), 256, 0, stream>>>(obj, tbin, cand, ccnt);
    sort_local_kernel<<<dim3(NBATCH * (CANDCAP / SORT_CHUNK)), 512, 0, stream>>>(cand);
    sort_merge_kernel<<<dim3(NBATCH), 1024, 0, stream>>>(cand, obj, topk, flags);
    decode_kernel    <<<dim3((PRE_NMS + 255) / 256, NBATCH), 256, 0, stream>>>(
        anchors, deltas, topk, imh, imw, boxes, areas, validm);
    mask_kernel      <<<dim3((PRE_NMS / TI) * NBATCH), 256, 0, stream>>>(
        boxes, areas, maskp, diag);
    scan_kernel      <<<dim3(NBATCH), 64, 0, stream>>>(
        maskp, diag, validm, boxes, flags, ccnt, out);
    (void)in_sizes; (void)n_in; (void)ws_size;
}